// Round 1
// baseline (424.926 us; speedup 1.0000x reference)
//
#include <hip/hip_runtime.h>

// Problem: B=256, F=32, N=16, D=512
//   sims[b,f,c,n] = relu(face[b,f]·ner[c,n])       (8192 x 4096 NT GEMM, K=512)
//   S_all[b,f]    = sum_{c,n} masked(sims)          (masked: ==1.0 -> 0)
//   pos[b,f]      = sum_n sims[b,f,b,n]             (UNmasked diagonal)
//   diag_m[b,f]   = sum_n masked(sims[b,f,b,n])
//   neg           = (S_all - diag_m) / 255.0
//   loss = sum(relu(neg - pos + 0.2) * face_mask) / 256

#define DIM_B 256
#define DIM_F 32
#define DIM_N 16
#define DIM_D 512
#define M_TOT (DIM_B * DIM_F)   // 8192
#define N_TOT (DIM_B * DIM_N)   // 4096

#define BM 128
#define BN 128
#define BK 32

// ---------------------------------------------------------------------------
// Main GEMM: C = face * ner^T, fused relu + (==1 -> 0) mask + row-sum.
// One atomicAdd per row per block into S_all.
// ---------------------------------------------------------------------------
__global__ __launch_bounds__(256) void grl_gemm_rowsum(
    const float* __restrict__ A, const float* __restrict__ Bn,
    float* __restrict__ S_all) {
  __shared__ float As[BK][BM + 4];
  __shared__ float Bs[BK][BN + 4];
  const int tid = threadIdx.x;
  const int tx = tid & 15;   // 16 col-thread groups
  const int ty = tid >> 4;   // 16 row-thread groups
  const int m0 = blockIdx.x * BM;
  const int n0 = blockIdx.y * BN;

  float acc[8][8];
#pragma unroll
  for (int i = 0; i < 8; ++i)
#pragma unroll
    for (int j = 0; j < 8; ++j) acc[i][j] = 0.0f;

  for (int k0 = 0; k0 < DIM_D; k0 += BK) {
    __syncthreads();
    // Stage 128x32 tiles of A and B (coalesced float4 along K, transposed in LDS)
#pragma unroll
    for (int i = 0; i < 4; ++i) {
      const int idx4 = tid + i * 256;
      const int row = idx4 >> 3;          // 0..127
      const int k4 = (idx4 & 7) << 2;     // 0,4,..,28
      const float4 av = *(const float4*)(A + (size_t)(m0 + row) * DIM_D + k0 + k4);
      As[k4 + 0][row] = av.x; As[k4 + 1][row] = av.y;
      As[k4 + 2][row] = av.z; As[k4 + 3][row] = av.w;
      const float4 bv = *(const float4*)(Bn + (size_t)(n0 + row) * DIM_D + k0 + k4);
      Bs[k4 + 0][row] = bv.x; Bs[k4 + 1][row] = bv.y;
      Bs[k4 + 2][row] = bv.z; Bs[k4 + 3][row] = bv.w;
    }
    __syncthreads();
#pragma unroll
    for (int k = 0; k < BK; ++k) {
      float a[8], b[8];
      *(float4*)&a[0] = *(const float4*)&As[k][ty * 8];
      *(float4*)&a[4] = *(const float4*)&As[k][ty * 8 + 4];
      *(float4*)&b[0] = *(const float4*)&Bs[k][tx * 8];
      *(float4*)&b[4] = *(const float4*)&Bs[k][tx * 8 + 4];
#pragma unroll
      for (int i = 0; i < 8; ++i)
#pragma unroll
        for (int j = 0; j < 8; ++j) acc[i][j] = fmaf(a[i], b[j], acc[i][j]);
    }
  }

  // Fused epilogue: relu, ==1->0 mask, per-thread row sums
  float rowsum[8];
#pragma unroll
  for (int i = 0; i < 8; ++i) {
    float s = 0.0f;
#pragma unroll
    for (int j = 0; j < 8; ++j) {
      float v = acc[i][j] > 0.0f ? acc[i][j] : 0.0f;
      v = (v == 1.0f) ? 0.0f : v;
      s += v;
    }
    rowsum[i] = s;
  }

  // Cross-thread (tx) reduction per row, reusing As as scratch
  __syncthreads();
  float* red = &As[0][0];  // needs 128*17 = 2176 floats (< 32*132)
#pragma unroll
  for (int i = 0; i < 8; ++i) red[(ty * 8 + i) * 17 + tx] = rowsum[i];
  __syncthreads();
  if (tid < BM) {
    float s = 0.0f;
#pragma unroll
    for (int t = 0; t < 16; ++t) s += red[tid * 17 + t];
    atomicAdd(&S_all[m0 + tid], s);
  }
}

// ---------------------------------------------------------------------------
// Diagonal slice (c == b): pos (unmasked), diag_m (masked), and face_mask.
// One wave per (b,f) row; 16 dots of length 512 each.
// ---------------------------------------------------------------------------
__global__ __launch_bounds__(256) void grl_diag(
    const float* __restrict__ face, const float* __restrict__ ner,
    float* __restrict__ pos, float* __restrict__ diagm,
    float* __restrict__ mask) {
  const int wid = threadIdx.x >> 6;
  const int lane = threadIdx.x & 63;
  const int row = blockIdx.x * 4 + wid;   // (b,f) flat
  const int b = row >> 5;
  const float* fp = face + (size_t)row * DIM_D;

  float fv[8];
  float fsum = 0.0f;
#pragma unroll
  for (int i = 0; i < 8; ++i) {
    fv[i] = fp[lane + i * 64];
    fsum += fv[i];
  }
#pragma unroll
  for (int off = 1; off < 64; off <<= 1) fsum += __shfl_xor(fsum, off);

  float posAcc = 0.0f, dmAcc = 0.0f;
  for (int n = 0; n < DIM_N; ++n) {
    const float* np_ = ner + ((size_t)b * DIM_N + n) * DIM_D;
    float p = 0.0f;
#pragma unroll
    for (int i = 0; i < 8; ++i) p = fmaf(fv[i], np_[lane + i * 64], p);
#pragma unroll
    for (int off = 1; off < 64; off <<= 1) p += __shfl_xor(p, off);
    float v = p > 0.0f ? p : 0.0f;
    posAcc += v;
    dmAcc += (v == 1.0f) ? 0.0f : v;
  }
  if (lane == 0) {
    pos[row] = posAcc;
    diagm[row] = dmAcc;
    mask[row] = (fsum != 0.0f) ? 1.0f : 0.0f;
  }
}

// ---------------------------------------------------------------------------
// Finalize: rank + global sum. Single block.
// ---------------------------------------------------------------------------
__global__ __launch_bounds__(256) void grl_final(
    const float* __restrict__ S_all, const float* __restrict__ diagm,
    const float* __restrict__ pos, const float* __restrict__ mask,
    float* __restrict__ out) {
  __shared__ float red[256];
  float s = 0.0f;
  for (int r = threadIdx.x; r < M_TOT; r += 256) {
    const float neg = (S_all[r] - diagm[r]) / 255.0f;  // 255 + 1e-8 == 255.0f in fp32
    float rank = neg - pos[r] + 0.2f;
    rank = rank > 0.0f ? rank : 0.0f;
    s += rank * mask[r];
  }
  red[threadIdx.x] = s;
  __syncthreads();
  for (int off = 128; off > 0; off >>= 1) {
    if (threadIdx.x < off) red[threadIdx.x] += red[threadIdx.x + off];
    __syncthreads();
  }
  if (threadIdx.x == 0) out[0] = red[0] / 256.0f;  // BETA * sum / B
}

// ---------------------------------------------------------------------------
extern "C" void kernel_launch(void* const* d_in, const int* in_sizes, int n_in,
                              void* d_out, int out_size, void* d_ws, size_t ws_size,
                              hipStream_t stream) {
  const float* face = (const float*)d_in[0];
  const float* ner = (const float*)d_in[1];
  float* ws = (float*)d_ws;
  float* S_all = ws;                // 8192
  float* diagm = ws + M_TOT;        // 8192
  float* pos = ws + 2 * M_TOT;      // 8192
  float* mask = ws + 3 * M_TOT;     // 8192

  hipMemsetAsync(S_all, 0, M_TOT * sizeof(float), stream);  // atomics target
  grl_diag<<<M_TOT / 4, 256, 0, stream>>>(face, ner, pos, diagm, mask);
  grl_gemm_rowsum<<<dim3(M_TOT / BM, N_TOT / BN), 256, 0, stream>>>(face, ner, S_all);
  grl_final<<<1, 256, 0, stream>>>(S_all, diagm, pos, mask, (float*)d_out);
}

// Round 2
// 92.738 us; speedup vs baseline: 4.5820x; 4.5820x over previous
//
#include <hip/hip_runtime.h>

// Problem: B=256, F=32, N=16, D=512
//   sims[b,f,c,n] = relu(face[b,f]·ner[c,n])       (8192 x 4096 NT GEMM, K=512)
//   S_all[b,f]    = sum_{c,n} masked(sims)          (masked: ==1.0 -> 0)
//   pos[b,f]      = sum_n sims[b,f,b,n]             (UNmasked diagonal, fp32)
//   diag_m[b,f]   = sum_n masked(sims[b,f,b,n])     (fp32)
//   neg           = (S_all - diag_m) / 255.0
//   loss = sum(relu(neg - pos + 0.2) * face_mask) / 256
//
// Round 2: bf16 MFMA GEMM (16x16x32), global_load_lds width=16 staging with
// XOR-swizzled k-blocks (both-sides swizzle, rule #21), fused rowsum epilogue.
// pos/diag_m/mask stay fp32 for accuracy. Fp32 fallback if ws too small.

#define DIM_B 256
#define DIM_F 32
#define DIM_N 16
#define DIM_D 512
#define M_TOT (DIM_B * DIM_F)   // 8192
#define N_TOT (DIM_B * DIM_N)   // 4096

typedef __attribute__((ext_vector_type(8))) short short8v;
typedef __attribute__((ext_vector_type(4))) float f32x4;

// ---------------------------------------------------------------------------
// fp32 -> bf16 (RNE) conversion, float4 in / ushort4 out
// ---------------------------------------------------------------------------
__device__ __forceinline__ unsigned short f2bf(float f) {
  unsigned int u = __builtin_bit_cast(unsigned int, f);
  u += 0x7fffu + ((u >> 16) & 1u);
  return (unsigned short)(u >> 16);
}

__global__ __launch_bounds__(256) void cvt_bf16(const float* __restrict__ in,
                                                unsigned short* __restrict__ out,
                                                int n4) {
  const int i = blockIdx.x * 256 + threadIdx.x;
  if (i >= n4) return;
  const float4 f = ((const float4*)in)[i];
  ushort4 o;
  o.x = f2bf(f.x); o.y = f2bf(f.y); o.z = f2bf(f.z); o.w = f2bf(f.w);
  ((ushort4*)out)[i] = o;
}

// ---------------------------------------------------------------------------
// bf16 MFMA GEMM with fused relu + (==1 -> 0) + row-sum epilogue.
// 128x128 tile, BK=32, 4 waves (2x2), each wave 64x64 = 4x4 frags of 16x16.
// LDS: A/B tiles [128 rows][4 k-slots of 8 bf16], slot s of row r holds
// global k-block (s ^ ((r>>1)&3))  -> 16B-granular spread, 2-way max alias.
// Staged with global_load_lds (dst linear, source pre-swizzled).
// ---------------------------------------------------------------------------
__global__ __launch_bounds__(256) void grl_gemm_bf16(
    const unsigned short* __restrict__ A, const unsigned short* __restrict__ Bn,
    float* __restrict__ S_all) {
  __shared__ __align__(16) unsigned short As[128 * 32];
  __shared__ __align__(16) unsigned short Bs[128 * 32];

  const int tid = threadIdx.x;
  const int lane = tid & 63;
  const int wid = tid >> 6;
  const int wr = wid >> 1;        // wave row (0..1)
  const int wc = wid & 1;         // wave col (0..1)
  const int m0 = blockIdx.x * 128;
  const int n0 = blockIdx.y * 128;

  // ---- stager per-lane setup (2 instrs per matrix per wave) ----
  // instr i covers rows [ (wid*2+i)*16 , +16 ), lane: row += lane>>2, slot = lane&3
  // global k-block fetched for slot s at row r:  g = s ^ ((r>>1)&3) = (lane&3)^((lane>>3)&3)
  const int g = (lane & 3) ^ ((lane >> 3) & 3);
  const int r0 = wid * 32 + (lane >> 2);
  const int r1 = r0 + 16;
  const unsigned short* gA0 = A + (size_t)(m0 + r0) * DIM_D + g * 8;
  const unsigned short* gA1 = A + (size_t)(m0 + r1) * DIM_D + g * 8;
  const unsigned short* gB0 = Bn + (size_t)(n0 + r0) * DIM_D + g * 8;
  const unsigned short* gB1 = Bn + (size_t)(n0 + r1) * DIM_D + g * 8;
  unsigned short* lA0 = As + (wid * 2 + 0) * 512;   // wave-uniform LDS bases
  unsigned short* lA1 = As + (wid * 2 + 1) * 512;
  unsigned short* lB0 = Bs + (wid * 2 + 0) * 512;
  unsigned short* lB1 = Bs + (wid * 2 + 1) * 512;

  // ---- reader per-lane setup ----
  // frag row r = tile_r + (lane&15), k-block kb = lane>>4,
  // swizzled slot = kb ^ ((r>>1)&3) = (lane>>4) ^ ((lane>>1)&3)
  const int slotR = (lane >> 4) ^ ((lane >> 1) & 3);
  const int aoff = (lane & 15) * 32 + slotR * 8;   // in shorts (row stride 32)

  f32x4 acc[4][4];
#pragma unroll
  for (int i = 0; i < 4; ++i)
#pragma unroll
    for (int j = 0; j < 4; ++j) acc[i][j] = (f32x4){0.f, 0.f, 0.f, 0.f};

  for (int k0 = 0; k0 < DIM_D; k0 += 32) {
    __builtin_amdgcn_global_load_lds(
        (const __attribute__((address_space(1))) void*)(gA0 + k0),
        (__attribute__((address_space(3))) void*)lA0, 16, 0, 0);
    __builtin_amdgcn_global_load_lds(
        (const __attribute__((address_space(1))) void*)(gA1 + k0),
        (__attribute__((address_space(3))) void*)lA1, 16, 0, 0);
    __builtin_amdgcn_global_load_lds(
        (const __attribute__((address_space(1))) void*)(gB0 + k0),
        (__attribute__((address_space(3))) void*)lB0, 16, 0, 0);
    __builtin_amdgcn_global_load_lds(
        (const __attribute__((address_space(1))) void*)(gB1 + k0),
        (__attribute__((address_space(3))) void*)lB1, 16, 0, 0);
    __syncthreads();   // compiler drains vmcnt(0) here

    short8v af[4], bfr[4];
#pragma unroll
    for (int mi = 0; mi < 4; ++mi)
      af[mi] = *(const short8v*)(As + (wr * 64 + mi * 16) * 32 + aoff);
#pragma unroll
    for (int ni = 0; ni < 4; ++ni)
      bfr[ni] = *(const short8v*)(Bs + (wc * 64 + ni * 16) * 32 + aoff);
#pragma unroll
    for (int mi = 0; mi < 4; ++mi)
#pragma unroll
      for (int ni = 0; ni < 4; ++ni)
        acc[mi][ni] = __builtin_amdgcn_mfma_f32_16x16x32_bf16(
            af[mi], bfr[ni], acc[mi][ni], 0, 0, 0);
    __syncthreads();
  }

  // ---- fused epilogue: relu, ==1->0, row sums ----
  // C/D layout (m89-verified): col = lane&15 (n), row = (lane>>4)*4 + reg (m)
  float rsum[4][4];   // [mi][reg]
#pragma unroll
  for (int mi = 0; mi < 4; ++mi)
#pragma unroll
    for (int r = 0; r < 4; ++r) rsum[mi][r] = 0.0f;
#pragma unroll
  for (int mi = 0; mi < 4; ++mi)
#pragma unroll
    for (int ni = 0; ni < 4; ++ni)
#pragma unroll
      for (int r = 0; r < 4; ++r) {
        float v = acc[mi][ni][r];
        v = v > 0.0f ? v : 0.0f;
        v = (v == 1.0f) ? 0.0f : v;
        rsum[mi][r] += v;
      }

#pragma unroll
  for (int mi = 0; mi < 4; ++mi)
#pragma unroll
    for (int r = 0; r < 4; ++r) {
      float s = rsum[mi][r];
      s += __shfl_xor(s, 1);
      s += __shfl_xor(s, 2);
      s += __shfl_xor(s, 4);
      s += __shfl_xor(s, 8);
      if ((lane & 15) == 0)
        atomicAdd(&S_all[m0 + wr * 64 + mi * 16 + (lane >> 4) * 4 + r], s);
    }
}

// ---------------------------------------------------------------------------
// fp32 fallback GEMM (round-1 kernel, used only if ws too small)
// ---------------------------------------------------------------------------
#define BM 128
#define BN 128
#define BK 32
__global__ __launch_bounds__(256) void grl_gemm_rowsum(
    const float* __restrict__ A, const float* __restrict__ Bn,
    float* __restrict__ S_all) {
  __shared__ float As[BK][BM + 4];
  __shared__ float Bs[BK][BN + 4];
  const int tid = threadIdx.x;
  const int tx = tid & 15;
  const int ty = tid >> 4;
  const int m0 = blockIdx.x * BM;
  const int n0 = blockIdx.y * BN;

  float acc[8][8];
#pragma unroll
  for (int i = 0; i < 8; ++i)
#pragma unroll
    for (int j = 0; j < 8; ++j) acc[i][j] = 0.0f;

  for (int k0 = 0; k0 < DIM_D; k0 += BK) {
    __syncthreads();
#pragma unroll
    for (int i = 0; i < 4; ++i) {
      const int idx4 = tid + i * 256;
      const int row = idx4 >> 3;
      const int k4 = (idx4 & 7) << 2;
      const float4 av = *(const float4*)(A + (size_t)(m0 + row) * DIM_D + k0 + k4);
      As[k4 + 0][row] = av.x; As[k4 + 1][row] = av.y;
      As[k4 + 2][row] = av.z; As[k4 + 3][row] = av.w;
      const float4 bv = *(const float4*)(Bn + (size_t)(n0 + row) * DIM_D + k0 + k4);
      Bs[k4 + 0][row] = bv.x; Bs[k4 + 1][row] = bv.y;
      Bs[k4 + 2][row] = bv.z; Bs[k4 + 3][row] = bv.w;
    }
    __syncthreads();
#pragma unroll
    for (int k = 0; k < BK; ++k) {
      float a[8], b[8];
      *(float4*)&a[0] = *(const float4*)&As[k][ty * 8];
      *(float4*)&a[4] = *(const float4*)&As[k][ty * 8 + 4];
      *(float4*)&b[0] = *(const float4*)&Bs[k][tx * 8];
      *(float4*)&b[4] = *(const float4*)&Bs[k][tx * 8 + 4];
#pragma unroll
      for (int i = 0; i < 8; ++i)
#pragma unroll
        for (int j = 0; j < 8; ++j) acc[i][j] = fmaf(a[i], b[j], acc[i][j]);
    }
  }
  float rowsum[8];
#pragma unroll
  for (int i = 0; i < 8; ++i) {
    float s = 0.0f;
#pragma unroll
    for (int j = 0; j < 8; ++j) {
      float v = acc[i][j] > 0.0f ? acc[i][j] : 0.0f;
      v = (v == 1.0f) ? 0.0f : v;
      s += v;
    }
    rowsum[i] = s;
  }
  __syncthreads();
  float* red = &As[0][0];
#pragma unroll
  for (int i = 0; i < 8; ++i) red[(ty * 8 + i) * 17 + tx] = rowsum[i];
  __syncthreads();
  if (tid < BM) {
    float s = 0.0f;
#pragma unroll
    for (int t = 0; t < 16; ++t) s += red[tid * 17 + t];
    atomicAdd(&S_all[m0 + tid], s);
  }
}

// ---------------------------------------------------------------------------
// Diagonal slice (c == b): pos (unmasked), diag_m (masked), face_mask. fp32.
// ---------------------------------------------------------------------------
__global__ __launch_bounds__(256) void grl_diag(
    const float* __restrict__ face, const float* __restrict__ ner,
    float* __restrict__ pos, float* __restrict__ diagm,
    float* __restrict__ mask) {
  const int wid = threadIdx.x >> 6;
  const int lane = threadIdx.x & 63;
  const int row = blockIdx.x * 4 + wid;   // (b,f) flat
  const int b = row >> 5;
  const float* fp = face + (size_t)row * DIM_D;

  float fv[8];
  float fsum = 0.0f;
#pragma unroll
  for (int i = 0; i < 8; ++i) {
    fv[i] = fp[lane + i * 64];
    fsum += fv[i];
  }
#pragma unroll
  for (int off = 1; off < 64; off <<= 1) fsum += __shfl_xor(fsum, off);

  float posAcc = 0.0f, dmAcc = 0.0f;
  for (int n = 0; n < DIM_N; ++n) {
    const float* np_ = ner + ((size_t)b * DIM_N + n) * DIM_D;
    float p = 0.0f;
#pragma unroll
    for (int i = 0; i < 8; ++i) p = fmaf(fv[i], np_[lane + i * 64], p);
#pragma unroll
    for (int off = 1; off < 64; off <<= 1) p += __shfl_xor(p, off);
    float v = p > 0.0f ? p : 0.0f;
    posAcc += v;
    dmAcc += (v == 1.0f) ? 0.0f : v;
  }
  if (lane == 0) {
    pos[row] = posAcc;
    diagm[row] = dmAcc;
    mask[row] = (fsum != 0.0f) ? 1.0f : 0.0f;
  }
}

// ---------------------------------------------------------------------------
// Finalize: rank + global sum. Single block.
// ---------------------------------------------------------------------------
__global__ __launch_bounds__(256) void grl_final(
    const float* __restrict__ S_all, const float* __restrict__ diagm,
    const float* __restrict__ pos, const float* __restrict__ mask,
    float* __restrict__ out) {
  __shared__ float red[256];
  float s = 0.0f;
  for (int r = threadIdx.x; r < M_TOT; r += 256) {
    const float neg = (S_all[r] - diagm[r]) / 255.0f;
    float rank = neg - pos[r] + 0.2f;
    rank = rank > 0.0f ? rank : 0.0f;
    s += rank * mask[r];
  }
  red[threadIdx.x] = s;
  __syncthreads();
  for (int off = 128; off > 0; off >>= 1) {
    if (threadIdx.x < off) red[threadIdx.x] += red[threadIdx.x + off];
    __syncthreads();
  }
  if (threadIdx.x == 0) out[0] = red[0] / 256.0f;
}

// ---------------------------------------------------------------------------
extern "C" void kernel_launch(void* const* d_in, const int* in_sizes, int n_in,
                              void* d_out, int out_size, void* d_ws, size_t ws_size,
                              hipStream_t stream) {
  const float* face = (const float*)d_in[0];
  const float* ner = (const float*)d_in[1];

  const size_t bfBytes = (size_t)(M_TOT + N_TOT) * DIM_D * sizeof(unsigned short);
  const size_t need = bfBytes + (size_t)4 * M_TOT * sizeof(float) + 256;

  if (ws_size >= need) {
    unsigned short* face_bf = (unsigned short*)d_ws;
    unsigned short* ner_bf = face_bf + (size_t)M_TOT * DIM_D;
    float* S_all = (float*)(ner_bf + (size_t)N_TOT * DIM_D);
    float* diagm = S_all + M_TOT;
    float* pos = diagm + M_TOT;
    float* mask = pos + M_TOT;

    hipMemsetAsync(S_all, 0, M_TOT * sizeof(float), stream);
    cvt_bf16<<<(M_TOT * DIM_D / 4 + 255) / 256, 256, 0, stream>>>(face, face_bf,
                                                                  M_TOT * DIM_D / 4);
    cvt_bf16<<<(N_TOT * DIM_D / 4 + 255) / 256, 256, 0, stream>>>(ner, ner_bf,
                                                                  N_TOT * DIM_D / 4);
    grl_diag<<<M_TOT / 4, 256, 0, stream>>>(face, ner, pos, diagm, mask);
    grl_gemm_bf16<<<dim3(M_TOT / 128, N_TOT / 128), 256, 0, stream>>>(face_bf, ner_bf,
                                                                      S_all);
    grl_final<<<1, 256, 0, stream>>>(S_all, diagm, pos, mask, (float*)d_out);
  } else {
    float* ws = (float*)d_ws;
    float* S_all = ws;
    float* diagm = ws + M_TOT;
    float* pos = ws + 2 * M_TOT;
    float* mask = ws + 3 * M_TOT;

    hipMemsetAsync(S_all, 0, M_TOT * sizeof(float), stream);
    grl_diag<<<M_TOT / 4, 256, 0, stream>>>(face, ner, pos, diagm, mask);
    grl_gemm_rowsum<<<dim3(M_TOT / BM, N_TOT / BN), 256, 0, stream>>>(face, ner, S_all);
    grl_final<<<1, 256, 0, stream>>>(S_all, diagm, pos, mask, (float*)d_out);
  }
}

// Round 4
// 70.677 us; speedup vs baseline: 6.0122x; 1.3121x over previous
//
#include <hip/hip_runtime.h>

// B=256, F=32, N=16, D=512
//   sims[b,f,c,n] = relu(face[b,f]·ner[c,n])      (8192 x 4096 NT GEMM, K=512)
//   S_all[b,f]    = sum_{c,n} masked(sims)        (masked: ==1.0 -> 0)
//   pos[b,f]      = sum_n sims[b,f,b,n]           (unmasked diagonal)
//   diag_m[b,f]   = sum_n masked(sims[b,f,b,n])
//   loss = sum(relu((S_all-diag_m)/255 - pos + 0.2) * face_mask) / 256
//
// Round 4: (round-3 design, compile fixed). 256x256 tile, BK=32, 8 waves,
// 4-deep LDS ring with counted vmcnt(8) (T3+T4), setprio around MFMA
// clusters (T5), XOR k-slot swizzle (T2, both-sides with global_load_lds).
// Diagonal (pos/diag_m) extracted from MFMA accumulators in diagonal blocks.

#define DIM_D 512
#define M_TOT 8192
#define N_TOT 4096

typedef __attribute__((ext_vector_type(8))) short short8v;
typedef __attribute__((ext_vector_type(4))) float f32x4;

__device__ __forceinline__ unsigned short f2bf(float f) {
  unsigned int u = __builtin_bit_cast(unsigned int, f);
  u += 0x7fffu + ((u >> 16) & 1u);
  return (unsigned short)(u >> 16);
}

// ---------------------------------------------------------------------------
// Merged cvt: face+ner fp32 -> bf16, plus face_mask (fp32 row-sum != 0).
// One wave per 512-elem row.
// ---------------------------------------------------------------------------
__global__ __launch_bounds__(256) void cvt_all(
    const float* __restrict__ face, const float* __restrict__ ner,
    unsigned short* __restrict__ face_bf, unsigned short* __restrict__ ner_bf,
    float* __restrict__ mask) {
  const int gw = blockIdx.x * 4 + (threadIdx.x >> 6);
  const int lane = threadIdx.x & 63;
  const bool isFace = gw < M_TOT;
  const int row = isFace ? gw : gw - M_TOT;
  const float* src = (isFace ? face : ner) + (size_t)row * DIM_D;
  unsigned short* dst = (isFace ? face_bf : ner_bf) + (size_t)row * DIM_D;

  const float4 f0 = ((const float4*)src)[lane * 2];
  const float4 f1 = ((const float4*)src)[lane * 2 + 1];
  short8v o;
  o[0] = (short)f2bf(f0.x); o[1] = (short)f2bf(f0.y);
  o[2] = (short)f2bf(f0.z); o[3] = (short)f2bf(f0.w);
  o[4] = (short)f2bf(f1.x); o[5] = (short)f2bf(f1.y);
  o[6] = (short)f2bf(f1.z); o[7] = (short)f2bf(f1.w);
  *(short8v*)(dst + lane * 8) = o;

  if (isFace) {
    float fs = f0.x + f0.y + f0.z + f0.w + f1.x + f1.y + f1.z + f1.w;
#pragma unroll
    for (int off = 1; off < 64; off <<= 1) fs += __shfl_xor(fs, off);
    if (lane == 0) mask[row] = (fs != 0.0f) ? 1.0f : 0.0f;
  }
}

// ---------------------------------------------------------------------------
// 256x256 bf16 MFMA GEMM, BK=32, 8 waves (2M x 4N), per-wave 128x64 output.
// 4-deep K-tile LDS ring (4 x 32KB = 128 KiB), counted vmcnt(8).
// LDS layout per tile: A [256 rows][4 slots x 8 bf16], slot s of row r holds
// k-block s ^ ((r>>1)&3)  (16B granularity; ds_read_b128 -> 2-way = free).
// ---------------------------------------------------------------------------
#define MFMA(A_, B_, C_) __builtin_amdgcn_mfma_f32_16x16x32_bf16(A_, B_, C_, 0, 0, 0)

#define GLDS(SRC, DSTOFF)                                                     \
  __builtin_amdgcn_global_load_lds(                                           \
      (const __attribute__((address_space(1))) void*)(SRC),                   \
      (__attribute__((address_space(3))) void*)(lds + (DSTOFF)), 16, 0, 0)

__global__ __launch_bounds__(512) void grl_gemm256(
    const unsigned short* __restrict__ A, const unsigned short* __restrict__ Bn,
    float* __restrict__ S_all, float* __restrict__ pos,
    float* __restrict__ diagm) {
  extern __shared__ unsigned short lds[];  // 4 tiles x (A 8192 + B 8192) shorts

  const int tid = threadIdx.x;
  const int lane = tid & 63;
  const int wid = tid >> 6;
  const int wr = wid >> 2;   // 0..1  (M)
  const int wc = wid & 3;    // 0..3  (N)
  const int m0 = blockIdx.x * 256;
  const int n0 = blockIdx.y * 256;

  // --- staging setup: 4 global_load_lds per tile per thread -------------
  const int g = (lane & 3) ^ ((lane >> 3) & 3);    // pre-swizzled k-block
  const int srow = wid * 16 + (lane >> 2);         // 0..127
  const unsigned short* gA0 = A + (size_t)(m0 + srow) * DIM_D + g * 8;
  const unsigned short* gA1 = gA0 + (size_t)128 * DIM_D;
  const unsigned short* gB0 = Bn + (size_t)(n0 + srow) * DIM_D + g * 8;
  const unsigned short* gB1 = gB0 + (size_t)128 * DIM_D;
  const int ldsw = wid * 512;  // wave-uniform base within each 4096-short half

#define STAGE_A(T)                                   \
  do {                                               \
    const int bo_ = ((T) & 3) * 16384;               \
    GLDS(gA0 + (T) * 32, bo_ + ldsw);                \
    GLDS(gA1 + (T) * 32, bo_ + 4096 + ldsw);         \
  } while (0)
#define STAGE_B(T)                                   \
  do {                                               \
    const int bo_ = ((T) & 3) * 16384;               \
    GLDS(gB0 + (T) * 32, bo_ + 8192 + ldsw);         \
    GLDS(gB1 + (T) * 32, bo_ + 12288 + ldsw);        \
  } while (0)

  // --- reader setup: swizzled fragment offset (shorts) ------------------
  const int foff = (lane & 15) * 32 + (((lane >> 4) ^ ((lane >> 1) & 3)) * 8);

  f32x4 acc[8][4];
#pragma unroll
  for (int i = 0; i < 8; ++i)
#pragma unroll
    for (int j = 0; j < 4; ++j) acc[i][j] = (f32x4){0.f, 0.f, 0.f, 0.f};

  short8v a0, a1, a2, a3, a4, a5, a6, a7, b0, b1, b2, b3;

#define MROW(AR, M)                             \
  acc[M][0] = MFMA(AR, b0, acc[M][0]);          \
  acc[M][1] = MFMA(AR, b1, acc[M][1]);          \
  acc[M][2] = MFMA(AR, b2, acc[M][2]);          \
  acc[M][3] = MFMA(AR, b3, acc[M][3]);

#define PH0(T, STG)                                                     \
  do {                                                                  \
    const unsigned short* Ab = lds + ((T) & 3) * 16384;                 \
    const unsigned short* Bb = Ab + 8192;                               \
    b0 = *(const short8v*)(Bb + (wc * 64 + 0) * 32 + foff);             \
    b1 = *(const short8v*)(Bb + (wc * 64 + 16) * 32 + foff);            \
    b2 = *(const short8v*)(Bb + (wc * 64 + 32) * 32 + foff);            \
    b3 = *(const short8v*)(Bb + (wc * 64 + 48) * 32 + foff);            \
    a0 = *(const short8v*)(Ab + (wr * 128 + 0) * 32 + foff);            \
    a1 = *(const short8v*)(Ab + (wr * 128 + 16) * 32 + foff);           \
    a2 = *(const short8v*)(Ab + (wr * 128 + 32) * 32 + foff);           \
    a3 = *(const short8v*)(Ab + (wr * 128 + 48) * 32 + foff);           \
    if (STG) STAGE_A((T) + 3);                                          \
    __builtin_amdgcn_s_barrier();                                       \
    __builtin_amdgcn_s_setprio(1);                                      \
    MROW(a0, 0) MROW(a1, 1) MROW(a2, 2) MROW(a3, 3)                     \
    __builtin_amdgcn_s_setprio(0);                                      \
    __builtin_amdgcn_s_barrier();                                       \
  } while (0)

#define PH1(T, STG, KEEPSTR)                                            \
  do {                                                                  \
    const unsigned short* Ab = lds + ((T) & 3) * 16384;                 \
    a4 = *(const short8v*)(Ab + (wr * 128 + 64) * 32 + foff);           \
    a5 = *(const short8v*)(Ab + (wr * 128 + 80) * 32 + foff);           \
    a6 = *(const short8v*)(Ab + (wr * 128 + 96) * 32 + foff);           \
    a7 = *(const short8v*)(Ab + (wr * 128 + 112) * 32 + foff);          \
    if (STG) STAGE_B((T) + 3);                                          \
    __builtin_amdgcn_s_barrier();                                       \
    __builtin_amdgcn_s_setprio(1);                                      \
    MROW(a4, 4) MROW(a5, 5) MROW(a6, 6) MROW(a7, 7)                     \
    __builtin_amdgcn_s_setprio(0);                                      \
    asm volatile("s_waitcnt vmcnt(" KEEPSTR ")" ::: "memory");          \
    __builtin_amdgcn_s_barrier();                                       \
  } while (0)

#define PH1_LAST(T)                                                     \
  do {                                                                  \
    const unsigned short* Ab = lds + ((T) & 3) * 16384;                 \
    a4 = *(const short8v*)(Ab + (wr * 128 + 64) * 32 + foff);           \
    a5 = *(const short8v*)(Ab + (wr * 128 + 80) * 32 + foff);           \
    a6 = *(const short8v*)(Ab + (wr * 128 + 96) * 32 + foff);           \
    a7 = *(const short8v*)(Ab + (wr * 128 + 112) * 32 + foff);          \
    __builtin_amdgcn_s_setprio(1);                                      \
    MROW(a4, 4) MROW(a5, 5) MROW(a6, 6) MROW(a7, 7)                     \
    __builtin_amdgcn_s_setprio(0);                                      \
  } while (0)

  // --- prologue: stage tiles 0,1,2 (12 loads in flight) ------------------
  STAGE_A(0); STAGE_B(0);
  STAGE_A(1); STAGE_B(1);
  STAGE_A(2); STAGE_B(2);
  asm volatile("s_waitcnt vmcnt(8)" ::: "memory");  // tile 0 landed
  __builtin_amdgcn_s_barrier();

  // --- main loop: tiles 0..12, stage tile t+3, counted vmcnt(8) ----------
  for (int t = 0; t < 13; ++t) {
    PH0(t, 1);
    PH1(t, 1, "8");
  }
  // --- tail: no staging, drain 8 -> 4 -> 0 -------------------------------
  PH0(13, 0); PH1(13, 0, "4");
  PH0(14, 0); PH1(14, 0, "0");
  PH0(15, 0); PH1_LAST(15);

  // --- epilogue: relu + (==1 -> 0) + row sums ---------------------------
  // C/D layout: col = lane&15, row(frag) = (lane>>4)*4 + reg
  float rsum[8][4];
#pragma unroll
  for (int mi = 0; mi < 8; ++mi)
#pragma unroll
    for (int r = 0; r < 4; ++r) rsum[mi][r] = 0.0f;
#pragma unroll
  for (int mi = 0; mi < 8; ++mi)
#pragma unroll
    for (int ni = 0; ni < 4; ++ni)
#pragma unroll
      for (int r = 0; r < 4; ++r) {
        float v = acc[mi][ni][r];
        v = v > 0.0f ? v : 0.0f;
        v = (v == 1.0f) ? 0.0f : v;
        rsum[mi][r] += v;
      }
#pragma unroll
  for (int mi = 0; mi < 8; ++mi)
#pragma unroll
    for (int r = 0; r < 4; ++r) {
      float s = rsum[mi][r];
      s += __shfl_xor(s, 1);
      s += __shfl_xor(s, 2);
      s += __shfl_xor(s, 4);
      s += __shfl_xor(s, 8);
      if ((lane & 15) == 0)
        atomicAdd(&S_all[m0 + wr * 128 + mi * 16 + (lane >> 4) * 4 + r], s);
    }

  // --- fused diagonal: block (bx, bx>>1) holds cols [16b,16b+16) for its b's
  if (blockIdx.y == (blockIdx.x >> 1)) {
#pragma unroll
    for (int mi = 0; mi < 8; ++mi) {
      const int R0 = m0 + wr * 128 + mi * 16;     // rows R0..R0+15 share b
      const int tcol = ((R0 >> 5) << 4) - n0;     // diag col offset in tile
      if ((tcol >> 6) == wc) {
        const int dn = (tcol >> 4) & 3;
#pragma unroll
        for (int ni = 0; ni < 4; ++ni)
          if (ni == dn) {
#pragma unroll
            for (int r = 0; r < 4; ++r) {
              float v = acc[mi][ni][r];
              v = v > 0.0f ? v : 0.0f;
              float vm = (v == 1.0f) ? 0.0f : v;
              float ps = v, ds = vm;
              ps += __shfl_xor(ps, 1); ds += __shfl_xor(ds, 1);
              ps += __shfl_xor(ps, 2); ds += __shfl_xor(ds, 2);
              ps += __shfl_xor(ps, 4); ds += __shfl_xor(ds, 4);
              ps += __shfl_xor(ps, 8); ds += __shfl_xor(ds, 8);
              if ((lane & 15) == 0) {
                const int R = R0 + (lane >> 4) * 4 + r;
                pos[R] = ps;
                diagm[R] = ds;
              }
            }
          }
      }
    }
  }
}

// ---------------------------------------------------------------------------
// Finalize: rank + global sum. Single block, 1024 threads.
// ---------------------------------------------------------------------------
__global__ __launch_bounds__(1024) void grl_final(
    const float* __restrict__ S_all, const float* __restrict__ diagm,
    const float* __restrict__ pos, const float* __restrict__ mask,
    float* __restrict__ out) {
  __shared__ float red[16];
  const int lane = threadIdx.x & 63;
  const int wv = threadIdx.x >> 6;
  float s = 0.0f;
  for (int r = threadIdx.x; r < M_TOT; r += 1024) {
    const float neg = (S_all[r] - diagm[r]) / 255.0f;  // 255 + 1e-8 == 255.0f
    float rank = neg - pos[r] + 0.2f;
    rank = rank > 0.0f ? rank : 0.0f;
    s += rank * mask[r];
  }
#pragma unroll
  for (int off = 1; off < 64; off <<= 1) s += __shfl_xor(s, off);
  if (lane == 0) red[wv] = s;
  __syncthreads();
  if (threadIdx.x == 0) {
    float t = 0.0f;
#pragma unroll
    for (int i = 0; i < 16; ++i) t += red[i];
    out[0] = t / 256.0f;  // BETA * sum / B
  }
}

// ---------------------------------------------------------------------------
extern "C" void kernel_launch(void* const* d_in, const int* in_sizes, int n_in,
                              void* d_out, int out_size, void* d_ws, size_t ws_size,
                              hipStream_t stream) {
  const float* face = (const float*)d_in[0];
  const float* ner = (const float*)d_in[1];

  unsigned short* face_bf = (unsigned short*)d_ws;
  unsigned short* ner_bf = face_bf + (size_t)M_TOT * DIM_D;
  float* S_all = (float*)(ner_bf + (size_t)N_TOT * DIM_D);
  float* diagm = S_all + M_TOT;
  float* pos = diagm + M_TOT;
  float* mask = pos + M_TOT;

  hipFuncSetAttribute((const void*)grl_gemm256,
                      hipFuncAttributeMaxDynamicSharedMemorySize, 131072);

  hipMemsetAsync(S_all, 0, M_TOT * sizeof(float), stream);
  cvt_all<<<(M_TOT + N_TOT) / 4, 256, 0, stream>>>(face, ner, face_bf, ner_bf,
                                                   mask);
  grl_gemm256<<<dim3(M_TOT / 256, N_TOT / 256), 512, 131072, stream>>>(
      face_bf, ner_bf, S_all, pos, diagm);
  grl_final<<<1, 1024, 0, stream>>>(S_all, diagm, pos, mask, (float*)d_out);
}